// Round 2
// baseline (552.451 us; speedup 1.0000x reference)
//
#include <hip/hip_runtime.h>
#include <stdint.h>

// HunyuanVideo attn block: rmsnorm -> qkv proj -> frame-causal attention -> out proj + residual
// B=1, C=512, T=8, H=W=32 -> S=8192, frame block = 1024.
// v2: attention rebuilt: V^T global layout + global_load_lds staging (double-buffered),
//     K read straight from global (L1-shared across the block's 4 waves),
//     (f+1)-way balanced kv-split -> 576 equal blocks of 32 kv-tiles each.

typedef __bf16 bf16;
typedef __bf16 bf16x8 __attribute__((ext_vector_type(8)));
typedef float f32x4 __attribute__((ext_vector_type(4)));
typedef uint32_t u32;
typedef uint32_t u32x2 __attribute__((ext_vector_type(2)));

#define MFMA16(a, b, c) __builtin_amdgcn_mfma_f32_16x16x32_bf16((a), (b), (c), 0, 0, 0)

__device__ __forceinline__ u32 pack2(float a, float b) {
  union { bf16 h[2]; u32 u; } x;
  x.h[0] = (bf16)a;
  x.h[1] = (bf16)b;
  return x.u;
}

__device__ __forceinline__ void async_copy16(const bf16* gsrc, bf16* ldst) {
  __builtin_amdgcn_global_load_lds(
      (const __attribute__((address_space(1))) void*)gsrc,
      (__attribute__((address_space(3))) void*)ldst, 16, 0, 0);
}

// ---------------- weights fp32 -> bf16 ----------------
__global__ void cvt_w_kernel(const float* __restrict__ a, const float* __restrict__ b,
                             const float* __restrict__ c, const float* __restrict__ d,
                             bf16* __restrict__ out) {
  int i = blockIdx.x * 256 + threadIdx.x;
  const int N = 512 * 512;
  out[i]         = (bf16)a[i];
  out[N + i]     = (bf16)b[i];
  out[2 * N + i] = (bf16)c[i];
  out[3 * N + i] = (bf16)d[i];
}

// ---------------- rmsnorm over C + transpose to [S][C] bf16 ----------------
__global__ __launch_bounds__(256) void rmsnorm_kernel(const float* __restrict__ x,
                                                      const float* __restrict__ gamma,
                                                      bf16* __restrict__ xn) {
  const int S = 8192;
  __shared__ float sums[4][64];
  int ts = threadIdx.x & 63, tc = threadIdx.x >> 6;
  int s = blockIdx.x * 64 + ts;
  float acc = 0.f;
  for (int c = tc * 128; c < tc * 128 + 128; ++c) {
    float v = x[(size_t)c * S + s];
    acc += v * v;
  }
  sums[tc][ts] = acc;
  __syncthreads();
  float tot = sums[0][ts] + sums[1][ts] + sums[2][ts] + sums[3][ts];
  float kk = 22.62741699796952f / fmaxf(sqrtf(tot), 1e-12f);
  for (int c0 = tc * 128; c0 < tc * 128 + 128; c0 += 8) {
    bf16x8 o;
#pragma unroll
    for (int j = 0; j < 8; ++j) o[j] = (bf16)(x[(size_t)(c0 + j) * S + s] * kk * gamma[c0 + j]);
    *(bf16x8*)(xn + (size_t)s * 512 + c0) = o;
  }
}

// ---------------- NT GEMM: C[m,n] = sum_k A[m,k]*B[n,k], K=512 ----------------
// EPI 0: out bf16 [M][N], += bias[n]                       (Q,K projections)
// EPI 1: out f32  [M][N], += bias[m] + resid[m*N+n]        (final projection + residual)
// EPI 2: out bf16 [M][N], += bias[m]                       (V^T projection: M=C rows)
template <int EPI>
__global__ __launch_bounds__(256) void gemm_nt_kernel(const bf16* __restrict__ A,
                                                      const bf16* __restrict__ B,
                                                      const float* __restrict__ bias,
                                                      const float* __restrict__ resid,
                                                      void* __restrict__ Cout, int M, int N,
                                                      int nbn) {
  __shared__ bf16 a_lds[128 * 72];
  __shared__ bf16 b_lds[128 * 72];
  const int K = 512;
  int bm = blockIdx.x / nbn, bn = blockIdx.x % nbn;
  int m0 = bm * 128, n0 = bn * 128;
  int tid = threadIdx.x, lane = tid & 63;
  int wid = tid >> 6;
  int wm = (wid >> 1) * 64, wn = (wid & 1) * 64;
  int l15 = lane & 15, l4 = lane >> 4;
  f32x4 acc[4][4];
#pragma unroll
  for (int i = 0; i < 4; ++i)
#pragma unroll
    for (int j = 0; j < 4; ++j) acc[i][j] = (f32x4){0.f, 0.f, 0.f, 0.f};

  for (int k0 = 0; k0 < K; k0 += 64) {
    __syncthreads();
#pragma unroll
    for (int i = 0; i < 4; ++i) {
      int lin = i * 2048 + tid * 8;
      int r = lin >> 6, c = lin & 63;
      *(bf16x8*)(a_lds + r * 72 + c) = *(const bf16x8*)(A + (size_t)(m0 + r) * K + k0 + c);
      *(bf16x8*)(b_lds + r * 72 + c) = *(const bf16x8*)(B + (size_t)(n0 + r) * K + k0 + c);
    }
    __syncthreads();
#pragma unroll
    for (int kk = 0; kk < 2; ++kk) {
      bf16x8 af[4], bfr[4];
#pragma unroll
      for (int i = 0; i < 4; ++i)
        af[i] = *(bf16x8*)(a_lds + (wm + i * 16 + l15) * 72 + kk * 32 + l4 * 8);
#pragma unroll
      for (int j = 0; j < 4; ++j)
        bfr[j] = *(bf16x8*)(b_lds + (wn + j * 16 + l15) * 72 + kk * 32 + l4 * 8);
#pragma unroll
      for (int i = 0; i < 4; ++i)
#pragma unroll
        for (int j = 0; j < 4; ++j) acc[i][j] = MFMA16(af[i], bfr[j], acc[i][j]);
    }
  }
#pragma unroll
  for (int i = 0; i < 4; ++i)
#pragma unroll
    for (int j = 0; j < 4; ++j) {
      int col = n0 + wn + j * 16 + l15;
#pragma unroll
      for (int r = 0; r < 4; ++r) {
        int row = m0 + wm + i * 16 + l4 * 4 + r;
        float v = acc[i][j][r];
        if (EPI == 0) {
          ((bf16*)Cout)[(size_t)row * N + col] = (bf16)(v + bias[col]);
        } else if (EPI == 1) {
          size_t idx = (size_t)row * N + col;
          ((float*)Cout)[idx] = v + bias[row] + resid[idx];
        } else {
          ((bf16*)Cout)[(size_t)row * N + col] = (bf16)(v + bias[row]);
        }
      }
    }
}

// ---------------- flash attention, frame-block causal, balanced kv-split ----------------
// 576 blocks: frame f contributes 16 q-subtiles x (f+1) kv-parts, each exactly 32 kv-tiles.
// 256 threads = 4 waves; wave owns 16 q-rows (swapped QK^T, layouts as v1).
// K: b128 loads straight from global (tile is L1-resident, shared by 4 waves).
// V^T: [512][32] bf16 tiles staged via global_load_lds, double-buffered.
__global__ __launch_bounds__(256, 2) void attn_kernel(const bf16* __restrict__ Qg,
                                                      const bf16* __restrict__ Kg,
                                                      const bf16* __restrict__ VT,
                                                      bf16* __restrict__ Oat,
                                                      bf16* __restrict__ Opart,
                                                      float2* __restrict__ mlbuf) {
  const float SC2 = 1.4426950408889634f / 22.627416997969522f;  // (1/sqrt(512))*log2(e)
  __shared__ bf16 vt_lds[2][512 * 32];  // [buf][d][32 kv] linear (32KB each)
  __shared__ u32 p_lds[4][16 * 20];     // per-wave P rows, packed kv-pairs

  // decode block -> (frame f, q-subtile qi, kv-part p)
  int rem = blockIdx.x;
  int f = 0;
  while (rem >= 16 * (f + 1)) { rem -= 16 * (f + 1); ++f; }
  int qi = rem & 15;
  int p = rem >> 4;
  int q0 = f * 1024 + qi * 64;
  int kvbase = p * 1024;

  int tid = threadIdx.x;
  int wid = tid >> 6;
  int lane = tid & 63;
  int l15 = lane & 15, l4 = lane >> 4;

  int qrow = q0 + wid * 16 + l15;
  bf16x8 qreg[16];
#pragma unroll
  for (int ks = 0; ks < 16; ++ks)
    qreg[ks] = *(const bf16x8*)(Qg + (size_t)qrow * 512 + ks * 32 + l4 * 8);

  f32x4 oacc[32];
#pragma unroll
  for (int i = 0; i < 32; ++i) oacc[i] = (f32x4){0.f, 0.f, 0.f, 0.f};
  float m2 = -1e30f, lsum = 0.f;

  // stage V^T tile (32KB): wave w covers d-rows [w*128,(w+1)*128), 8 async 1KB chunks
  const bf16* vsrc0 = VT + (size_t)(wid * 128 + (lane >> 2)) * 8192 + (lane & 3) * 8;
  auto stage = [&](int buf, int kv0s) {
    const bf16* src = vsrc0 + kv0s;
#pragma unroll
    for (int i = 0; i < 8; ++i)
      async_copy16(src + (size_t)i * 16 * 8192, &vt_lds[buf][wid * 4096 + i * 512]);
  };

  stage(0, kvbase);
  __syncthreads();

  const bf16* krow0 = Kg + (size_t)(kvbase + l15) * 512 + l4 * 8;
  const bf16* krow1 = krow0 + 16 * 512;

  for (int t = 0; t < 32; ++t) {
    int cur = t & 1;
    if (t + 1 < 32) stage(cur ^ 1, kvbase + (t + 1) * 32);

    // QK^T -> S^T[kv 32][q 16] straight from global K
    f32x4 sacc0 = {0.f, 0.f, 0.f, 0.f}, sacc1 = {0.f, 0.f, 0.f, 0.f};
    const bf16* k0 = krow0 + (size_t)t * 32 * 512;
    const bf16* k1 = krow1 + (size_t)t * 32 * 512;
#pragma unroll
    for (int ks = 0; ks < 16; ++ks) {
      bf16x8 a0 = *(const bf16x8*)(k0 + ks * 32);
      bf16x8 a1 = *(const bf16x8*)(k1 + ks * 32);
      sacc0 = MFMA16(a0, qreg[ks], sacc0);
      sacc1 = MFMA16(a1, qreg[ks], sacc1);
    }

    // online softmax for column q = l15
    float pmax = -1e30f;
#pragma unroll
    for (int r = 0; r < 4; ++r) {
      pmax = fmaxf(pmax, sacc0[r]);
      pmax = fmaxf(pmax, sacc1[r]);
    }
    pmax = fmaxf(pmax, __shfl_xor(pmax, 16));
    pmax = fmaxf(pmax, __shfl_xor(pmax, 32));
    pmax *= SC2;
    bool skip = (m2 > -1e29f) && (__all(pmax <= m2 + 11.5415603f) != 0);  // defer-max THR=8
    float m2n = skip ? m2 : fmaxf(m2, pmax);
    float pr[8];
    float psum = 0.f;
#pragma unroll
    for (int r = 0; r < 4; ++r) {
      pr[r] = exp2f(sacc0[r] * SC2 - m2n);
      pr[4 + r] = exp2f(sacc1[r] * SC2 - m2n);
      psum += pr[r] + pr[4 + r];
    }
    psum += __shfl_xor(psum, 16);
    psum += __shfl_xor(psum, 32);
    if (!skip) {
      float corr = exp2f(m2 - m2n);
      lsum = lsum * corr;
#pragma unroll
      for (int i = 0; i < 32; ++i) oacc[i] *= corr;
      m2 = m2n;
    }
    lsum += psum;

    // P -> p_lds[q][kv] (packed dwords); wave-private
    u32* prow = &p_lds[wid][l15 * 20];
    *(u32x2*)(prow + l4 * 2) = (u32x2){pack2(pr[0], pr[1]), pack2(pr[2], pr[3])};
    *(u32x2*)(prow + l4 * 2 + 8) = (u32x2){pack2(pr[4], pr[5]), pack2(pr[6], pr[7])};
    bf16x8 pfrag = *(bf16x8*)(prow + l4 * 4);

    // PV: O^T[d][q] += V^T[d][kv] * P[kv][q]   (linear V^T tile, conflict-free b128)
    const bf16* vb = vt_lds[cur];
#pragma unroll
    for (int df = 0; df < 32; ++df) {
      bf16x8 vf = *(const bf16x8*)(vb + (df * 16 + l15) * 32 + l4 * 8);
      oacc[df] = MFMA16(vf, pfrag, oacc[df]);
    }

    __syncthreads();  // drains stage(t+1) vmem + all lds; buffers swap safely
  }

  // write unnormalized partial (lane holds q=l15, d = df*16 + l4*4 + reg)
  int qr = q0 + wid * 16 + l15;
  bf16* op = (p == 0)
                 ? Oat + (size_t)qr * 512
                 : Opart + ((size_t)1024 * (f * (f - 1) / 2) + (size_t)(p - 1) * 1024 +
                            (qr & 1023)) * 512;
#pragma unroll
  for (int df = 0; df < 32; ++df) {
    int d = df * 16 + l4 * 4;
    u32x2 pk2 = {pack2(oacc[df][0], oacc[df][1]), pack2(oacc[df][2], oacc[df][3])};
    *(u32x2*)(op + d) = pk2;
  }
  if (l4 == 0) mlbuf[p * 8192 + qr] = make_float2(m2, lsum);
}

// ---------------- merge f+1 partials per row ----------------
__global__ void combine_kernel(const bf16* __restrict__ Opart, const float2* __restrict__ ml,
                               bf16* __restrict__ O) {
  int i = blockIdx.x * 256 + threadIdx.x;  // 8192 rows * 64 chunks of 8
  int row = i >> 6, dc = (i & 63) * 8;
  int f = row >> 10;
  float2 m0 = ml[row];
  float mm = m0.x;
  for (int p = 1; p <= f; ++p) mm = fmaxf(mm, ml[p * 8192 + row].x);
  float acc[8];
  float denom;
  {
    float w = exp2f(m0.x - mm);
    denom = w * m0.y;
    bf16x8 o = *(const bf16x8*)(O + (size_t)row * 512 + dc);
#pragma unroll
    for (int j = 0; j < 8; ++j) acc[j] = w * (float)o[j];
  }
  int rowin = row & 1023;
  size_t fbase = (size_t)1024 * (f * (f - 1) / 2);
  for (int p = 1; p <= f; ++p) {
    float2 mp = ml[p * 8192 + row];
    float w = exp2f(mp.x - mm);
    denom += w * mp.y;
    bf16x8 o = *(const bf16x8*)(Opart + (fbase + (size_t)(p - 1) * 1024 + rowin) * 512 + dc);
#pragma unroll
    for (int j = 0; j < 8; ++j) acc[j] += w * (float)o[j];
  }
  float inv = 1.f / denom;
  bf16x8 r;
#pragma unroll
  for (int j = 0; j < 8; ++j) r[j] = (bf16)(acc[j] * inv);
  *(bf16x8*)(O + (size_t)row * 512 + dc) = r;
}

extern "C" void kernel_launch(void* const* d_in, const int* in_sizes, int n_in, void* d_out,
                              int out_size, void* d_ws, size_t ws_size, hipStream_t stream) {
  (void)in_sizes; (void)n_in; (void)out_size; (void)ws_size;
  const float* x = (const float*)d_in[0];
  const float* gamma = (const float*)d_in[1];
  const float* wq = (const float*)d_in[2];
  const float* bq = (const float*)d_in[3];
  const float* wk = (const float*)d_in[4];
  const float* bk = (const float*)d_in[5];
  const float* wv = (const float*)d_in[6];
  const float* bv = (const float*)d_in[7];
  const float* wo = (const float*)d_in[8];
  const float* bo = (const float*)d_in[9];

  const size_t SC = (size_t)8192 * 512;
  bf16* wq_b = (bf16*)d_ws;            // 4 x 256K bf16 = 2MB
  bf16* wk_b = wq_b + 262144;
  bf16* wv_b = wk_b + 262144;
  bf16* wo_b = wv_b + 262144;
  bf16* xn_oat = wo_b + 262144;        // 8MB: xn, later reused as attn output (+partial 0)
  bf16* q = xn_oat + SC;               // 8MB
  bf16* k = q + SC;                    // 8MB
  bf16* vt = k + SC;                   // 8MB, V^T [512][8192]
  bf16* opart = vt + SC;               // 28672 rows x 512 bf16 = 28MB (partials 1..f)
  float2* ml = (float2*)(opart + (size_t)28672 * 512);  // 8*8192 float2 = 512KB

  cvt_w_kernel<<<1024, 256, 0, stream>>>(wq, wk, wv, wo, wq_b);
  rmsnorm_kernel<<<128, 256, 0, stream>>>(x, gamma, xn_oat);
  gemm_nt_kernel<0><<<256, 256, 0, stream>>>(xn_oat, wq_b, bq, nullptr, q, 8192, 512, 4);
  gemm_nt_kernel<0><<<256, 256, 0, stream>>>(xn_oat, wk_b, bk, nullptr, k, 8192, 512, 4);
  gemm_nt_kernel<2><<<256, 256, 0, stream>>>(wv_b, xn_oat, bv, nullptr, vt, 512, 8192, 64);
  attn_kernel<<<576, 256, 0, stream>>>(q, k, vt, xn_oat, opart, ml);
  combine_kernel<<<2048, 256, 0, stream>>>(opart, ml, xn_oat);
  gemm_nt_kernel<1><<<256, 256, 0, stream>>>(wo_b, xn_oat, bo, x, d_out, 512, 8192, 64);
}